// Round 1
// 17695.125 us; speedup vs baseline: 2.1746x; 2.1746x over previous
//
#include <hip/hip_runtime.h>
#include <math.h>

#define TT 1024
#define BB 64
#define HH 512
#define G4 2048            // 4*HH
#define NBLK 256
#define NTHR 1024          // 16 waves
#define KH (HH * BB)       // one [512][64] slab = 32768 elems

// out layout: seq [T][B][H] | h_n [L][B][H] | c_n [L][B][H]
#define HN_OFF ((size_t)TT * BB * HH)
#define CN_OFF (HN_OFF + (size_t)2 * BB * HH)

__device__ inline float sigm(float v) {
    return 1.0f / (1.0f + __expf(-v));
}
__device__ inline float tanh_fast(float v) {
    const float e = __expf(2.0f * v);
    return 1.0f - 2.0f / (e + 1.0f);
}

// Coherent (L2-bypassing, sc1) store: lands at the L3 coherence point so
// other XCDs can see it after their per-step buffer_inv. No wbl2 needed.
__device__ inline void store_coh(float* p, float v) {
    __hip_atomic_store(p, v, __ATOMIC_RELAXED, __HIP_MEMORY_SCOPE_AGENT);
}

// ---------------- phase A: transpose x [T][B][K] -> xT [T][K][B] ------------
extern "C" __global__ void __launch_bounds__(256)
xpose(const float* __restrict__ x, float* __restrict__ xT)
{
    __shared__ float tile[64][65];
    const int t   = blockIdx.x;
    const int kc  = blockIdx.y << 6;
    const int tid = threadIdx.x;

    const int kk = tid & 63;
    const int b0 = tid >> 6;
    const float* xp = x + (size_t)t * BB * HH;
    #pragma unroll
    for (int i = 0; i < 16; ++i) {
        const int b = b0 + (i << 2);
        tile[b][kk] = xp[(size_t)b * HH + kc + kk];
    }
    __syncthreads();
    const int b  = tid & 63;
    const int k0 = tid >> 6;
    float* xo = xT + (size_t)t * KH + (size_t)kc * BB;
    #pragma unroll
    for (int i = 0; i < 16; ++i) {
        const int kl = k0 + (i << 2);
        xo[kl * BB + b] = tile[b][kl];
    }
}

// ---------------- grid barrier: relaxed atomics, ONE buffer_inv per step ----
// All data that races across blocks is written with sc1 stores (store_coh),
// so the only cache maintenance needed is a single acquire fence (buffer_inv)
// per block per step to drop stale L1/L2 copies of the h-buffers.
__device__ inline void grid_barrier(unsigned* gbar, unsigned* groot,
                                    unsigned barIdx, int bid)
{
    __syncthreads();   // rendezvous + drains every wave's vmcnt (h-stores done)
    if (threadIdx.x == 0) {
        const int g = bid & 15;
        const unsigned old = __hip_atomic_fetch_add(
            &gbar[g * 16], 1u, __ATOMIC_RELAXED, __HIP_MEMORY_SCOPE_AGENT);
        if (old == barIdx * 16u + 15u) {
            // dependency on `old` orders this after the gbar add completed
            __hip_atomic_fetch_add(groot, 1u, __ATOMIC_RELAXED,
                                   __HIP_MEMORY_SCOPE_AGENT);
        }
        const unsigned tgt = (barIdx + 1u) * 16u;
        while (__hip_atomic_load(groot, __ATOMIC_RELAXED,
                                 __HIP_MEMORY_SCOPE_AGENT) < tgt) {
            __builtin_amdgcn_s_sleep(1);
        }
        // single L1+L2 invalidate for this CU/XCD, per step
        __builtin_amdgcn_fence(__ATOMIC_ACQUIRE, "agent");
    }
    __syncthreads();
}

// ---------------- phase B: pipelined persistent scan ------------------------
// 256 blocks x 16 waves. Block owns 2 hidden units per layer (8 gate rows each).
// Step s: L0 computes t0=s (s<TT), L1 computes t1=s-1 (s>=1).
// Wave roles (grp=w>>2): 0: L0 in-proj (xT), 1: L0 recur (h0buf),
//                        2: L1 in-proj (h0buf), 3: L1 recur (h1buf).
// kbase=(w&3)*128 -> each gemm's K=512 split over 4 waves (latency hiding).
// Weights (wave-uniform) live in LDS: immune to the per-step L2 invalidate.
// Wave 0 does L0 gate math, wave 1 does L1 gate math.
extern "C" __global__ void __launch_bounds__(NTHR)
lstm_scan(const float* __restrict__ h0,
          const float* __restrict__ c0,
          const float* __restrict__ Wih,
          const float* __restrict__ Whh,
          const float* __restrict__ bih,
          const float* __restrict__ bhh,
          const float* __restrict__ xT,
          float* __restrict__ out,
          float* __restrict__ h0buf,   // [2][512][64]
          float* __restrict__ h1buf,   // [2][512][64]
          unsigned* __restrict__ gbar,
          unsigned* __restrict__ groot)
{
    __shared__ float red[16][8][64];                 // 32 KB
    __shared__ __align__(16) float wlds[16][8][128]; // 64 KB (per-wave slices)

    const int tid  = threadIdx.x;
    const int lane = tid & 63;                                   // batch
    const int w    = __builtin_amdgcn_readfirstlane(tid >> 6);   // wave 0..15
    const int bid  = blockIdx.x;
    const int hk0  = bid << 1;

    const int kbase = (w & 3) << 7;   // 0,128,256,384
    const int grp   = w >> 2;         // 0..3

    const float* Wbase;
    if      (grp == 0) Wbase = Wih;
    else if (grp == 1) Wbase = Whh;
    else if (grp == 2) Wbase = Wih + (size_t)G4 * HH;
    else               Wbase = Whh + (size_t)G4 * HH;

    // Stage this wave's weight slice into LDS once: 8 rows x 128 floats.
    // Inner-loop weight reads become uniform-broadcast ds_read_b128 and are
    // untouched by the per-step cache invalidate.
    #pragma unroll
    for (int rr = 0; rr < 8; ++rr) {
        const int row = ((rr >> 1) << 9) + hk0 + (rr & 1);
        const float* src = Wbase + (size_t)row * HH + kbase;
        wlds[w][rr][lane]      = src[lane];
        wlds[w][rr][lane + 64] = src[lane + 64];
    }

    float creg[2] = {0.f, 0.f};  // wave0: L0 c-state; wave1: L1 c-state
    float bs[8];
    if (w == 0) {
        #pragma unroll
        for (int u = 0; u < 2; ++u) {
            const int hk = hk0 + u;
            store_coh(&h0buf[hk * BB + lane], h0[(size_t)lane * HH + hk]);
            creg[u] = c0[(size_t)lane * HH + hk];
        }
        #pragma unroll
        for (int rr = 0; rr < 8; ++rr) {
            const int row = ((rr >> 1) << 9) + hk0 + (rr & 1);
            bs[rr] = bih[row] + bhh[row];
        }
    } else if (w == 1) {
        #pragma unroll
        for (int u = 0; u < 2; ++u) {
            const int hk = hk0 + u;
            store_coh(&h1buf[hk * BB + lane], h0[(size_t)(BB + lane) * HH + hk]);
            creg[u] = c0[(size_t)(BB + lane) * HH + hk];
        }
        #pragma unroll
        for (int rr = 0; rr < 8; ++rr) {
            const int row = ((rr >> 1) << 9) + hk0 + (rr & 1);
            bs[rr] = bih[G4 + row] + bhh[G4 + row];
        }
    }

    unsigned barIdx = 0;
    grid_barrier(gbar, groot, barIdx, bid); ++barIdx;

    const float* wl = &wlds[w][0][0];   // [8][128], wave-uniform base

    for (int s = 0; s <= TT; ++s) {
        const float* act;
        if (grp == 0) {
            const int t0 = (s < TT) ? s : (TT - 1);
            act = xT + (size_t)t0 * KH + (size_t)kbase * BB;
        } else if (grp <= 2) {
            act = h0buf + (size_t)(s & 1) * KH + (size_t)kbase * BB;
        } else {
            act = h1buf + (size_t)((s + 1) & 1) * KH + (size_t)kbase * BB;
        }

        float acc[8];
        #pragma unroll
        for (int rr = 0; rr < 8; ++rr) acc[rr] = 0.0f;

        #pragma unroll 2
        for (int j = 0; j < 128; j += 4) {
            const float a0 = act[(j + 0) * BB + lane];
            const float a1 = act[(j + 1) * BB + lane];
            const float a2 = act[(j + 2) * BB + lane];
            const float a3 = act[(j + 3) * BB + lane];
            #pragma unroll
            for (int rr = 0; rr < 8; ++rr) {
                const float4 wv = *(const float4*)(wl + rr * 128 + j);
                acc[rr] = fmaf(a3, wv.w,
                           fmaf(a2, wv.z,
                            fmaf(a1, wv.y,
                             fmaf(a0, wv.x, acc[rr]))));
            }
        }

        #pragma unroll
        for (int rr = 0; rr < 8; ++rr) red[w][rr][lane] = acc[rr];
        __syncthreads();

        if (w == 0) {
            if (s < TT) {   // layer 0, t0 = s
                float g[8];
                #pragma unroll
                for (int rr = 0; rr < 8; ++rr) {
                    float t = red[0][rr][lane] + red[1][rr][lane]
                            + red[2][rr][lane] + red[3][rr][lane]
                            + red[4][rr][lane] + red[5][rr][lane]
                            + red[6][rr][lane] + red[7][rr][lane];
                    g[rr] = bs[rr] + t;
                }
                #pragma unroll
                for (int u = 0; u < 2; ++u) {
                    const float ig = sigm(g[0 + u]);
                    const float fg = sigm(g[2 + u]);
                    const float gg = tanh_fast(g[4 + u]);
                    const float og = sigm(g[6 + u]);
                    const float cn = fg * creg[u] + ig * gg;
                    const float hn = og * tanh_fast(cn);
                    creg[u] = cn;
                    const int hk = hk0 + u;
                    store_coh(&h0buf[(size_t)((s + 1) & 1) * KH + hk * BB + lane], hn);
                    if (s == TT - 1) {
                        out[HN_OFF + (size_t)lane * HH + hk] = hn;
                        out[CN_OFF + (size_t)lane * HH + hk] = cn;
                    }
                }
            }
        } else if (w == 1) {
            if (s >= 1) {   // layer 1, t1 = s-1
                const int t1 = s - 1;
                float g[8];
                #pragma unroll
                for (int rr = 0; rr < 8; ++rr) {
                    float t = red[8][rr][lane]  + red[9][rr][lane]
                            + red[10][rr][lane] + red[11][rr][lane]
                            + red[12][rr][lane] + red[13][rr][lane]
                            + red[14][rr][lane] + red[15][rr][lane];
                    g[rr] = bs[rr] + t;
                }
                #pragma unroll
                for (int u = 0; u < 2; ++u) {
                    const float ig = sigm(g[0 + u]);
                    const float fg = sigm(g[2 + u]);
                    const float gg = tanh_fast(g[4 + u]);
                    const float og = sigm(g[6 + u]);
                    const float cn = fg * creg[u] + ig * gg;
                    const float hn = og * tanh_fast(cn);
                    creg[u] = cn;
                    const int hk = hk0 + u;
                    store_coh(&h1buf[(size_t)(s & 1) * KH + hk * BB + lane], hn);
                    out[(size_t)t1 * BB * HH + (size_t)lane * HH + hk] = hn;
                    if (t1 == TT - 1) {
                        out[HN_OFF + (size_t)(BB + lane) * HH + hk] = hn;
                        out[CN_OFF + (size_t)(BB + lane) * HH + hk] = cn;
                    }
                }
            }
        }
        grid_barrier(gbar, groot, barIdx, bid); ++barIdx;
    }
}

// ---------------------------------------------------------------------------
extern "C" void kernel_launch(void* const* d_in, const int* in_sizes, int n_in,
                              void* d_out, int out_size, void* d_ws, size_t ws_size,
                              hipStream_t stream)
{
    (void)in_sizes; (void)n_in; (void)out_size; (void)ws_size;
    const float* x   = (const float*)d_in[0];
    const float* h0  = (const float*)d_in[1];
    const float* c0  = (const float*)d_in[2];
    const float* Wih = (const float*)d_in[3];
    const float* Whh = (const float*)d_in[4];
    const float* bih = (const float*)d_in[5];
    const float* bhh = (const float*)d_in[6];
    float* out = (float*)d_out;

    // ws: xT [T][512][64] (128 MB) | h0buf [2][512][64] | h1buf | barrier ctrs
    float* xT    = (float*)d_ws;
    float* h0buf = xT + (size_t)TT * KH;
    float* h1buf = h0buf + (size_t)2 * KH;
    unsigned* gbar  = (unsigned*)(h1buf + (size_t)2 * KH);
    unsigned* groot = gbar + 256;

    hipMemsetAsync(gbar, 0, (256 + 64) * sizeof(unsigned), stream);

    xpose<<<dim3(TT, 8), 256, 0, stream>>>(x, xT);

    void* args[] = {(void*)&h0, (void*)&c0, (void*)&Wih, (void*)&Whh,
                    (void*)&bih, (void*)&bhh, (void*)&xT, (void*)&out,
                    (void*)&h0buf, (void*)&h1buf, (void*)&gbar, (void*)&groot};
    hipLaunchCooperativeKernel((void*)lstm_scan, dim3(NBLK), dim3(NTHR),
                               args, 0, stream);
}